// Round 18
// baseline (359.070 us; speedup 1.0000x reference)
//
#include <hip/hip_runtime.h>
#include <hip/hip_bf16.h>

#define NT 100000
#define NT_PAD 100032     // 1563 * 64
#define BQ 1024
#define DD 256
#define NGROUPS 128
#define NTILES 1563       // ceil(100000/64)
#define TBLOCKS (NT_PAD / 4)   // 25008 blocks for t rows in normalize_all

typedef __attribute__((ext_vector_type(8))) short bf16x8;
typedef __attribute__((ext_vector_type(4))) float f32x4;

__device__ __forceinline__ unsigned short f2bf(float x) {
    union { float f; unsigned u; } a; a.f = x;
    unsigned r = (a.u + 0x7fffu + ((a.u >> 16) & 1u)) >> 16;  // RNE
    return (unsigned short)r;
}

// ---- normalize one fp32 row (256 elems) -> packed bf16 uint2 for this lane ----
__device__ __forceinline__ uint2 norm_row(const float* __restrict__ src, int lane) {
    float4 v = ((const float4*)src)[lane];
    float s = v.x * v.x + v.y * v.y + v.z * v.z + v.w * v.w;
    #pragma unroll
    for (int m = 1; m < 64; m <<= 1) s += __shfl_xor(s, m, 64);
    float sc = rsqrtf(fmaxf(s, 1e-24f));
    uint2 pk;
    pk.x = (unsigned)f2bf(v.x * sc) | ((unsigned)f2bf(v.y * sc) << 16);
    pk.y = (unsigned)f2bf(v.z * sc) | ((unsigned)f2bf(v.w * sc) << 16);
    return pk;
}

// ---- fused: zero accumulators + normalize q + (optionally) normalize t ----
template<bool DO_T>
__global__ void normalize_all(const float* __restrict__ q, const float* __restrict__ t,
                              unsigned short* __restrict__ qn, unsigned short* __restrict__ tn,
                              float* __restrict__ accz) {
    int lane = threadIdx.x & 63, wid = threadIdx.x >> 6;
    int b = blockIdx.x;
    if (b < 8) accz[b * 256 + threadIdx.x] = 0.f;   // acc_e(1024) + acc_ed(1024)

    if (DO_T && b < TBLOCKS) {
        int row = b * 4 + wid;                      // covers exactly NT_PAD rows
        uint2 pk; pk.x = 0u; pk.y = 0u;
        if (row < NT) pk = norm_row(t + (size_t)row * DD, lane);
        *(uint2*)&tn[(size_t)row * DD + lane * 4] = pk;
    } else {
        int qb = DO_T ? (b - TBLOCKS) : b;
        int row = qb * 4 + wid;                     // covers exactly BQ rows
        uint2 pk = norm_row(q + (size_t)row * DD, lane);
        *(uint2*)&qn[(size_t)row * DD + lane * 4] = pk;
    }
}

// ---- epilogue helpers (macros: no lambdas / reference params — r11 scratch lesson) ----
#define EP1(DOT, SE, SD)                                                    \
    do { float s_ = fmaf(-2.f, (DOT), 2.f);                                 \
         float d_ = __builtin_amdgcn_sqrtf(fmaxf(s_, 0.f));                 \
         float e_ = exp2f(-14.4269504089f * d_);   /* exp(-10d) */          \
         (SE) += e_; (SD) = fmaf(e_, d_, (SD)); } while (0)

#define EPM(DOT, SE, SD, IDX)                                               \
    do { float s_ = fmaf(-2.f, (DOT), 2.f);                                 \
         float d_ = __builtin_amdgcn_sqrtf(fmaxf(s_, 0.f));                 \
         float e_ = ((IDX) < NT) ? exp2f(-14.4269504089f * d_) : 0.f;       \
         (SE) += e_; (SD) = fmaf(e_, d_, (SD)); } while (0)

// ================= PRIMARY: direct-from-L2, register double-buffered =================
// Model after r12+r14: the r9 LDS kernel is ~75% wait (lockstep 2-barrier phases
// at 4 waves/SIMD); r12's barrier-free direct kernel failed only because the
// 64-reg budget allowed zero load buffering (serialized L2 latency).
// Fix: amdgpu_waves_per_eu(2,2) -> 256-reg budget at 2 waves/SIMD; next tile's
// 16 A-fragments (64 VGPR) load while current tile's 32 MFMAs + epilogue run.
// Unroll-by-2 with statically named sets aA/aB (rule #20: constant indices only).
// No barriers, no inline asm, no clobbers — compiler inserts counted vmcnt and
// hoists the independent loads. XCD decode g=blockIdx&127 keeps each group's
// t-stream on one XCD (r12: FETCH 52 MB = exactly one tn pass, verified).
// Budget: qf 64 (AGPR-parked) + aA 64 + aB 64 + acc 16 + temps ~= 230 <= 256.
// GATES: VGPR_Count >= 150 and WRITE_SIZE ~2 MB. VGPR<=100 or WRITE blowup
// -> attribute inert -> revert to r9 kernel.
__global__ __launch_bounds__(512)
__attribute__((amdgpu_waves_per_eu(2, 2)))
void knn_direct(const unsigned short* __restrict__ tn,
                const unsigned short* __restrict__ qn,
                float* __restrict__ acc_e,
                float* __restrict__ acc_ed) {
    const int tid = threadIdx.x;
    const int lane = tid & 63, w = tid >> 6;       // w in 0..7
    const int wr = w >> 1;                         // m-subtile 0..3
    const int wc = w & 1;                          // n-half 0..1
    const int quad = lane >> 4, l16 = lane & 15;

    const int g = blockIdx.x & (NGROUPS - 1);   // n-group (siblings share t tiles)
    const int mchunk = blockIdx.x >> 7;         // log2(NGROUPS) == 7
    const int mbase = mchunk * 128;

    // q fragments: 32 q-rows per wave (2 x 16), 8 ksteps
    bf16x8 qf[2][8];
    #pragma unroll
    for (int mi = 0; mi < 2; ++mi) {
        const unsigned short* qrow =
            qn + (size_t)(mbase + wr * 32 + mi * 16 + l16) * DD + quad * 8;
        #pragma unroll
        for (int ks = 0; ks < 8; ++ks)
            qf[mi][ks] = *(const bf16x8*)(qrow + ks * 32);
    }

    float se0 = 0.f, se1 = 0.f, sd0 = 0.f, sd1 = 0.f;

    // per-lane base into tile stream (same addressing as r12 — correctness-proven)
    const unsigned short* tb = tn + (size_t)g * 64 * DD
                                  + (size_t)(wc * 32 + l16) * DD + quad * 8;
    const size_t step = (size_t)NGROUPS * 64 * DD;

    bf16x8 aA[2][8], aB[2][8];   // two statically-named fragment sets (64 VGPR each)

#define LOAD_SET(S)                                                         \
    do {                                                                    \
        _Pragma("unroll")                                                   \
        for (int ks = 0; ks < 8; ++ks) {                                    \
            S[0][ks] = *(const bf16x8*)(tb + ks * 32);                      \
            S[1][ks] = *(const bf16x8*)(tb + 16 * DD + ks * 32);            \
        }                                                                   \
        tb += step;                                                         \
    } while (0)

#define COMPUTE_SET(S, TI)                                                  \
    do {                                                                    \
        f32x4 a00 = {0.f,0.f,0.f,0.f}, a01 = {0.f,0.f,0.f,0.f};             \
        f32x4 a10 = {0.f,0.f,0.f,0.f}, a11 = {0.f,0.f,0.f,0.f};             \
        _Pragma("unroll")                                                   \
        for (int ks = 0; ks < 8; ++ks) {                                    \
            a00 = __builtin_amdgcn_mfma_f32_16x16x32_bf16(S[0][ks], qf[0][ks], a00, 0,0,0); \
            a01 = __builtin_amdgcn_mfma_f32_16x16x32_bf16(S[0][ks], qf[1][ks], a01, 0,0,0); \
            a10 = __builtin_amdgcn_mfma_f32_16x16x32_bf16(S[1][ks], qf[0][ks], a10, 0,0,0); \
            a11 = __builtin_amdgcn_mfma_f32_16x16x32_bf16(S[1][ks], qf[1][ks], a11, 0,0,0); \
        }                                                                   \
        const int n0_ = (TI) * 64;                                          \
        if (n0_ + 64 <= NT) {                                               \
            _Pragma("unroll")                                               \
            for (int r = 0; r < 4; ++r) {                                   \
                EP1(a00[r], se0, sd0); EP1(a01[r], se1, sd1);               \
                EP1(a10[r], se0, sd0); EP1(a11[r], se1, sd1);               \
            }                                                               \
        } else {                                                            \
            const int nq_ = n0_ + wc * 32 + quad * 4;                       \
            _Pragma("unroll")                                               \
            for (int r = 0; r < 4; ++r) {                                   \
                EPM(a00[r], se0, sd0, nq_ + r);                             \
                EPM(a01[r], se1, sd1, nq_ + r);                             \
                EPM(a10[r], se0, sd0, nq_ + 16 + r);                        \
                EPM(a11[r], se1, sd1, nq_ + 16 + r);                        \
            }                                                               \
        }                                                                   \
    } while (0)

    int ti = g;
    LOAD_SET(aA);                      // tile ti
    for (;;) {
        const bool have1 = (ti + NGROUPS < NTILES);
        if (have1) LOAD_SET(aB);       // tile ti+128 loads fly under compute(aA)
        COMPUTE_SET(aA, ti);
        if (!have1) break;
        ti += NGROUPS;
        const bool have2 = (ti + NGROUPS < NTILES);
        if (have2) LOAD_SET(aA);       // tile ti+128 loads fly under compute(aB)
        COMPUTE_SET(aB, ti);
        if (!have2) break;
        ti += NGROUPS;
    }

#undef LOAD_SET
#undef COMPUTE_SET

    // reduce across quads (rows of D) — once per kernel
    #pragma unroll
    for (int m = 16; m <= 32; m <<= 1) {
        se0 += __shfl_xor(se0, m, 64);
        se1 += __shfl_xor(se1, m, 64);
        sd0 += __shfl_xor(sd0, m, 64);
        sd1 += __shfl_xor(sd1, m, 64);
    }

    if (quad == 0) {
        int m0 = mbase + wr * 32 + l16;
        atomicAdd(&acc_e[m0],       se0);
        atomicAdd(&acc_e[m0 + 16],  se1);
        atomicAdd(&acc_ed[m0],      sd0);
        atomicAdd(&acc_ed[m0 + 16], sd1);
    }
}

// ================= FALLBACK PATH (ws too small): r9-style LDS kernel =================
__global__ __launch_bounds__(512, 4) void knn_fallback(const float* __restrict__ t_raw,
                                                       const unsigned short* __restrict__ qn,
                                                       float* __restrict__ acc_e,
                                                       float* __restrict__ acc_ed) {
    __shared__ unsigned short t_lds[2][64 * DD];   // 2 x 32 KB

    const int tid = threadIdx.x;
    const int lane = tid & 63, w = tid >> 6;
    const int wr = w >> 1, wc = w & 1;
    const int quad = lane >> 4, l16 = lane & 15;
    const int swz = l16 & 7;

    const int g = blockIdx.x & (NGROUPS - 1);
    const int mchunk = blockIdx.x >> 7;
    const int mbase = mchunk * 128;

    bf16x8 qf[2][8];
    #pragma unroll
    for (int mi = 0; mi < 2; ++mi) {
        const unsigned short* qrow =
            qn + (size_t)(mbase + wr * 32 + mi * 16 + l16) * DD + quad * 8;
        #pragma unroll
        for (int ks = 0; ks < 8; ++ks)
            qf[mi][ks] = *(const bf16x8*)(qrow + ks * 32);
    }

    auto stage = [&](unsigned short* dst, int ti) {
        int n0 = ti * 64;
        for (int i = 0; i < 8; ++i) {
            int row = w * 8 + i;
            int n = n0 + row;
            float4 v = make_float4(0.f, 0.f, 0.f, 0.f);
            if (n < NT) v = ((const float4*)t_raw)[(size_t)n * 64 + lane];
            float s = v.x * v.x + v.y * v.y + v.z * v.z + v.w * v.w;
            #pragma unroll
            for (int m = 1; m < 64; m <<= 1) s += __shfl_xor(s, m, 64);
            float sc = rsqrtf(fmaxf(s, 1e-24f));
            uint2 pk;
            pk.x = (unsigned)f2bf(v.x * sc) | ((unsigned)f2bf(v.y * sc) << 16);
            pk.y = (unsigned)f2bf(v.z * sc) | ((unsigned)f2bf(v.w * sc) << 16);
            int kb16 = lane >> 1, half = lane & 1;
            *(uint2*)&dst[row * DD + (((kb16 ^ (row & 7)) << 3) + (half << 2))] = pk;
        }
    };

    float se0 = 0.f, se1 = 0.f, sd0 = 0.f, sd1 = 0.f;

    stage(t_lds[0], g);
    if (g + NGROUPS < NTILES) stage(t_lds[1], g + NGROUPS);

    int it = 0;
    for (int ti = g; ti < NTILES; ti += NGROUPS, ++it) {
        const unsigned short* buf = t_lds[it & 1];
        __syncthreads();

        f32x4 acc[2][2];
        #pragma unroll
        for (int ni = 0; ni < 2; ++ni)
            #pragma unroll
            for (int mi = 0; mi < 2; ++mi)
                acc[ni][mi] = (f32x4){0.f, 0.f, 0.f, 0.f};

        #pragma unroll
        for (int ks = 0; ks < 8; ++ks) {
            bf16x8 a[2];
            #pragma unroll
            for (int ni = 0; ni < 2; ++ni)
                a[ni] = *(const bf16x8*)
                    &buf[(wc * 32 + ni * 16 + l16) * DD + (((ks * 4 + quad) ^ swz) << 3)];
            #pragma unroll
            for (int ni = 0; ni < 2; ++ni)
                #pragma unroll
                for (int mi = 0; mi < 2; ++mi)
                    acc[ni][mi] = __builtin_amdgcn_mfma_f32_16x16x32_bf16(
                        a[ni], qf[mi][ks], acc[ni][mi], 0, 0, 0);
        }

        __syncthreads();
        if (ti + 2 * NGROUPS < NTILES) stage((unsigned short*)t_lds[it & 1], ti + 2 * NGROUPS);

        const int n0 = ti * 64;
        if (n0 + 64 <= NT) {
            #pragma unroll
            for (int ni = 0; ni < 2; ++ni)
                #pragma unroll
                for (int mi = 0; mi < 2; ++mi)
                    #pragma unroll
                    for (int r = 0; r < 4; ++r) {
                        float dot = acc[ni][mi][r];
                        if (mi == 0) { EP1(dot, se0, sd0); }
                        else         { EP1(dot, se1, sd1); }
                    }
        } else {
            const int nq = n0 + wc * 32 + quad * 4;
            #pragma unroll
            for (int ni = 0; ni < 2; ++ni)
                #pragma unroll
                for (int mi = 0; mi < 2; ++mi)
                    #pragma unroll
                    for (int r = 0; r < 4; ++r) {
                        float dot = acc[ni][mi][r];
                        if (mi == 0) { EPM(dot, se0, sd0, nq + ni * 16 + r); }
                        else         { EPM(dot, se1, sd1, nq + ni * 16 + r); }
                    }
        }
    }

    #pragma unroll
    for (int m = 16; m <= 32; m <<= 1) {
        se0 += __shfl_xor(se0, m, 64);
        se1 += __shfl_xor(se1, m, 64);
        sd0 += __shfl_xor(sd0, m, 64);
        sd1 += __shfl_xor(sd1, m, 64);
    }

    if (quad == 0) {
        int m0 = mbase + wr * 32 + l16;
        atomicAdd(&acc_e[m0],       se0);
        atomicAdd(&acc_e[m0 + 16],  se1);
        atomicAdd(&acc_ed[m0],      sd0);
        atomicAdd(&acc_ed[m0 + 16], sd1);
    }
}

__global__ void finalize(const float* __restrict__ acc_e, const float* __restrict__ acc_ed,
                         float* __restrict__ out) {
    int i = blockIdx.x * 256 + threadIdx.x;
    out[i] = acc_ed[i] / acc_e[i];
}

extern "C" void kernel_launch(void* const* d_in, const int* in_sizes, int n_in,
                              void* d_out, int out_size, void* d_ws, size_t ws_size,
                              hipStream_t stream) {
    const float* q = (const float*)d_in[0];   // [1024,256] fp32
    const float* t = (const float*)d_in[1];   // [100000,256] fp32
    float* out = (float*)d_out;               // [1024] fp32

    char* ws = (char*)d_ws;
    float* acc_e = (float*)ws;                               // 4 KB
    float* acc_ed = acc_e + BQ;                              // 4 KB
    unsigned short* qn = (unsigned short*)(ws + 8192);       // 512 KB
    unsigned short* tn = (unsigned short*)(ws + 8192 + (size_t)BQ * DD * 2);  // 51.2 MB

    size_t needed = 8192 + (size_t)BQ * DD * 2 + (size_t)NT_PAD * DD * 2;

    if (ws_size >= needed) {
        normalize_all<true><<<TBLOCKS + BQ / 4, 256, 0, stream>>>(q, t, qn, tn, acc_e);
        knn_direct<<<NGROUPS * 8, 512, 0, stream>>>(tn, qn, acc_e, acc_ed);
    } else {
        normalize_all<false><<<BQ / 4, 256, 0, stream>>>(q, t, qn, tn, acc_e);
        knn_fallback<<<NGROUPS * 8, 512, 0, stream>>>(t, qn, acc_e, acc_ed);
    }
    finalize<<<BQ / 256, 256, 0, stream>>>(acc_e, acc_ed, out);
}